// Round 2
// baseline (68326.160 us; speedup 1.0000x reference)
//
#include <hip/hip_runtime.h>

#define T_STEPS 256
#define BATCH   64
#define HID     1024
#define DIN     512
#define NCLS    1000
#define NBLK    256
#define HSZ     (BATCH * HID)   // 65536 floats per h buffer

// ---------------------------------------------------------------------------
// Persistent 2-layer ReLU RNN. 256 blocks x 1024 threads, all co-resident
// (64 KB LDS -> <=2 blocks/CU, 256 CUs => capacity 512 >= 256).
// Block bid: layer z = bid&1, j-tile jt = bid>>1 (8 rows of W each).
// Weights staged to LDS once; 257 phases separated by a device-scope grid
// barrier. Layer 2 runs one phase behind layer 1 (software pipeline).
// Thread slot: kh = t&3 (K/4 split, reduced via 2 shfl_xor rounds),
//              jp = (t>>2)&3 (2 j-rows each), b = t>>4 (batch row).
// Per 4-k step: 1 A float4 (global/L1) + 2 W float4 (LDS) + 8 FMAs.
// ---------------------------------------------------------------------------

__device__ __forceinline__ void grid_bar(int* cnt, int* gen, int want) {
    __threadfence();            // release this thread's stores (agent scope)
    __syncthreads();
    if (threadIdx.x == 0) {
        int old = __hip_atomic_fetch_add(cnt, 1, __ATOMIC_ACQ_REL, __HIP_MEMORY_SCOPE_AGENT);
        if (old == NBLK - 1) {
            __hip_atomic_store(cnt, 0, __ATOMIC_RELAXED, __HIP_MEMORY_SCOPE_AGENT);
            __hip_atomic_store(gen, want, __ATOMIC_RELEASE, __HIP_MEMORY_SCOPE_AGENT);
        } else {
            // safety cap: a bug fails validation instead of hanging the harness
            for (long it = 0; it < 20000000L; ++it) {
                if (__hip_atomic_load(gen, __ATOMIC_ACQUIRE, __HIP_MEMORY_SCOPE_AGENT) >= want)
                    break;
                __builtin_amdgcn_s_sleep(2);
            }
        }
    }
    __syncthreads();
    __threadfence();            // acquire side for upcoming A reads
}

// Accumulate 2 j-rows over this thread's K/4 slice of one segment.
// arow: A row base (float*, this b's row). wl: LDS weight base.
__device__ __forceinline__ void seg_acc(const float* arow, int Klen,
                                        const float* wl, int rowlen, int segoff,
                                        int kh, int jp,
                                        float& a0e, float& a0o, float& a1e, float& a1o) {
    const int kslice = Klen >> 2;
    const int kb = kh * kslice;
    const float* ap = arow + kb;
    const float* w0 = wl + (size_t)(jp * 2    ) * rowlen + segoff + kb;
    const float* w1 = wl + (size_t)(jp * 2 + 1) * rowlen + segoff + kb;
#pragma unroll 8
    for (int kk = 0; kk < kslice; kk += 4) {
        float4 av  = *(const float4*)(ap + kk);
        float4 wv0 = *(const float4*)(w0 + kk);
        float4 wv1 = *(const float4*)(w1 + kk);
        a0e += wv0.x * av.x; a0o += wv0.y * av.y;
        a0e += wv0.z * av.z; a0o += wv0.w * av.w;
        a1e += wv1.x * av.x; a1o += wv1.y * av.y;
        a1e += wv1.z * av.z; a1o += wv1.w * av.w;
    }
}

__global__ __launch_bounds__(1024)
void rnn_persist(const float* __restrict__ x,
                 const float* __restrict__ w_ih0, const float* __restrict__ w_hh0,
                 const float* __restrict__ w_ih1, const float* __restrict__ w_hh1,
                 float* h1pp, float* h2pp, int* bar) {
    __shared__ float wlds[8 * 2048];   // 64 KB: 8 j-rows x K (2048 L2 / 1536 L1)

    const int bid = blockIdx.x;
    const int z   = bid & 1;          // layer
    const int jt  = bid >> 1;         // 0..127
    const int j0  = jt * 8;
    const int t   = threadIdx.x;

    // ---- stage this block's weight slice into LDS (once) ----
    if (z == 0) {
        // row layout: [j][0..512) = w_ih0 row, [512..1536) = w_hh0 row
        for (int v = t; v < 3072; v += 1024) {          // 3072 float4s
            int j  = v / 384;                           // 384 f4 per row
            int kk = (v - j * 384) * 4;
            float4 val;
            if (kk < 512) val = *(const float4*)(w_ih0 + (size_t)(j0 + j) * DIN + kk);
            else          val = *(const float4*)(w_hh0 + (size_t)(j0 + j) * HID + (kk - 512));
            *(float4*)&wlds[(size_t)j * 1536 + kk] = val;
        }
    } else {
        // row layout: [j][0..1024) = w_ih1 row, [1024..2048) = w_hh1 row
        for (int v = t; v < 4096; v += 1024) {          // 4096 float4s
            int j  = v >> 9;                            // 512 f4 per row
            int kk = (v & 511) * 4;
            float4 val;
            if (kk < 1024) val = *(const float4*)(w_ih1 + (size_t)(j0 + j) * HID + kk);
            else           val = *(const float4*)(w_hh1 + (size_t)(j0 + j) * HID + (kk - 1024));
            *(float4*)&wlds[(size_t)j * 2048 + kk] = val;
        }
    }
    __syncthreads();

    const int kh = t & 3;
    const int jp = (t >> 2) & 3;
    const int b  = t >> 4;            // 0..63

    for (int p = 0; p <= T_STEPS; ++p) {
        const bool work = z ? (p >= 1) : (p < T_STEPS);
        if (work) {
            float a0e = 0.f, a0o = 0.f, a1e = 0.f, a1o = 0.f;
            float* outp;
            if (z == 0) {
                // h1_next = relu(W_ih0 x_p + W_hh0 h1_cur)
                const float* h1c = h1pp + (size_t)(p & 1) * HSZ;
                seg_acc(x + ((size_t)b * T_STEPS + p) * DIN, DIN,
                        wlds, 1536, 0, kh, jp, a0e, a0o, a1e, a1o);
                seg_acc(h1c + (size_t)b * HID, HID,
                        wlds, 1536, DIN, kh, jp, a0e, a0o, a1e, a1o);
                outp = h1pp + (size_t)((p + 1) & 1) * HSZ;
            } else {
                // q = p-1: h2_next = relu(W_ih1 h1_{q+1} + W_hh1 h2_q)
                const int q = p - 1;
                const float* h1n = h1pp + (size_t)(p & 1) * HSZ;
                const float* h2c = h2pp + (size_t)(q & 1) * HSZ;
                seg_acc(h1n + (size_t)b * HID, HID,
                        wlds, 2048, 0, kh, jp, a0e, a0o, a1e, a1o);
                seg_acc(h2c + (size_t)b * HID, HID,
                        wlds, 2048, HID, kh, jp, a0e, a0o, a1e, a1o);
                outp = h2pp + (size_t)((q + 1) & 1) * HSZ;
            }
            float a0 = a0e + a0o;
            float a1 = a1e + a1o;
            // reduce the 4 kh partials (lane bits 0,1 — quad-local)
            a0 += __shfl_xor(a0, 1, 64);
            a1 += __shfl_xor(a1, 1, 64);
            a0 += __shfl_xor(a0, 2, 64);
            a1 += __shfl_xor(a1, 2, 64);
            if (kh == 0) {
                const int j = j0 + jp * 2;
                float2 st;
                st.x = fmaxf(a0, 0.f);
                st.y = fmaxf(a1, 0.f);
                *(float2*)(outp + (size_t)b * HID + j) = st;
            }
        }
        grid_bar(&bar[0], &bar[1], p + 1);
    }
}

__global__ void zero_kernel(float* __restrict__ p, int n) {
    int i = blockIdx.x * blockDim.x + threadIdx.x;
    if (i < n) p[i] = 0.f;
}

// out[b][c] = sum_k h2[b][k] * w_fc[c][k];  grid (64, 4) x 256
__global__ void fc_kernel(const float* __restrict__ h2,
                          const float* __restrict__ w_fc,
                          float* __restrict__ out) {
    __shared__ float hs[HID];
    const int b = blockIdx.x;
    for (int i = threadIdx.x; i < HID; i += 256) hs[i] = h2[(size_t)b * HID + i];
    __syncthreads();
    const int c = blockIdx.y * 256 + threadIdx.x;
    if (c < NCLS) {
        const float* w = w_fc + (size_t)c * HID;
        float s = 0.f;
        for (int k = 0; k < HID; k += 4) {
            float4 wv = *(const float4*)(w + k);
            s += wv.x * hs[k] + wv.y * hs[k + 1] + wv.z * hs[k + 2] + wv.w * hs[k + 3];
        }
        out[(size_t)b * NCLS + c] = s;
    }
}

extern "C" void kernel_launch(void* const* d_in, const int* in_sizes, int n_in,
                              void* d_out, int out_size, void* d_ws, size_t ws_size,
                              hipStream_t stream) {
    const float* x     = (const float*)d_in[0];
    const float* w_ih0 = (const float*)d_in[1];
    const float* w_hh0 = (const float*)d_in[2];
    const float* w_ih1 = (const float*)d_in[3];
    const float* w_hh1 = (const float*)d_in[4];
    const float* w_fc  = (const float*)d_in[5];
    float* out = (float*)d_out;

    float* h1pp = (float*)d_ws;              // 2 x [64][1024]
    float* h2pp = h1pp + 2 * HSZ;            // 2 x [64][1024]
    int*   bar  = (int*)(h1pp + 4 * HSZ);    // {cnt, gen}
    const int nzero = 4 * HSZ + 16;          // h buffers + barrier state

    zero_kernel<<<(nzero + 255) / 256, 256, 0, stream>>>(h1pp, nzero);

    rnn_persist<<<NBLK, 1024, 0, stream>>>(x, w_ih0, w_hh0, w_ih1, w_hh1,
                                           h1pp, h2pp, bar);

    fc_kernel<<<dim3(64, 4), 256, 0, stream>>>(h2pp, w_fc, out);
}

// Round 3
// 32908.014 us; speedup vs baseline: 2.0763x; 2.0763x over previous
//
#include <hip/hip_runtime.h>

#define T_STEPS 256
#define BATCH   64
#define HID     1024
#define DIN     512
#define NCLS    1000
#define NBLK    512
#define HSZ     (BATCH * HID)   // 65536 elems per h buffer

typedef __attribute__((ext_vector_type(8))) short  short8;  // 8 bf16 (4 VGPRs)
typedef __attribute__((ext_vector_type(4))) float  f32x4;   // MFMA C/D

// round-to-nearest-even fp32 -> bf16 (as raw ushort)
__device__ __forceinline__ unsigned short rne_bf16(float f) {
    unsigned int u = __builtin_bit_cast(unsigned int, f);
    u += 0x7FFFu + ((u >> 16) & 1u);
    return (unsigned short)(u >> 16);
}
__device__ __forceinline__ float bf16_to_f(unsigned short h) {
    unsigned int u = ((unsigned int)h) << 16;
    return __builtin_bit_cast(float, u);
}

// ---------------------------------------------------------------------------
// One K-segment, A already split to bf16 hi/lo in memory.
// All pointers pre-offset to (row * K + koff); chunk c advances 32 elems.
// 3-pass Markidis: acc += Ah*Wh + Al*Wh + Ah*Wl  (fp32 accumulate).
// ---------------------------------------------------------------------------
__device__ __forceinline__ void seg_bf16(const unsigned short* __restrict__ Ahi,
                                         const unsigned short* __restrict__ Alo,
                                         const unsigned short* __restrict__ Whi,
                                         const unsigned short* __restrict__ Wlo,
                                         int K, f32x4& acc) {
    const int nch = K >> 5;
#pragma unroll 4
    for (int c = 0; c < nch; ++c) {
        short8 ah = *(const short8*)(Ahi + c * 32);
        short8 al = *(const short8*)(Alo + c * 32);
        short8 wh = *(const short8*)(Whi + c * 32);
        short8 wl = *(const short8*)(Wlo + c * 32);
        acc = __builtin_amdgcn_mfma_f32_16x16x32_bf16(ah, wh, acc, 0, 0, 0);
        acc = __builtin_amdgcn_mfma_f32_16x16x32_bf16(al, wh, acc, 0, 0, 0);
        acc = __builtin_amdgcn_mfma_f32_16x16x32_bf16(ah, wl, acc, 0, 0, 0);
    }
}

// Same, but A is fp32 in memory (the x input): split on the fly.
__device__ __forceinline__ void seg_f32A(const float* __restrict__ Arow,
                                         const unsigned short* __restrict__ Whi,
                                         const unsigned short* __restrict__ Wlo,
                                         int K, f32x4& acc) {
    const int nch = K >> 5;
#pragma unroll 4
    for (int c = 0; c < nch; ++c) {
        float4 a0 = *(const float4*)(Arow + c * 32);
        float4 a1 = *(const float4*)(Arow + c * 32 + 4);
        float f[8] = {a0.x, a0.y, a0.z, a0.w, a1.x, a1.y, a1.z, a1.w};
        short8 ah, al;
#pragma unroll
        for (int i = 0; i < 8; ++i) {
            unsigned short h = rne_bf16(f[i]);
            ah[i] = (short)h;
            al[i] = (short)rne_bf16(f[i] - bf16_to_f(h));
        }
        short8 wh = *(const short8*)(Whi + c * 32);
        short8 wl = *(const short8*)(Wlo + c * 32);
        acc = __builtin_amdgcn_mfma_f32_16x16x32_bf16(ah, wh, acc, 0, 0, 0);
        acc = __builtin_amdgcn_mfma_f32_16x16x32_bf16(al, wh, acc, 0, 0, 0);
        acc = __builtin_amdgcn_mfma_f32_16x16x32_bf16(ah, wl, acc, 0, 0, 0);
    }
}

// ---------------------------------------------------------------------------
// Persistent MFMA RNN. 512 blocks x 64 threads (1 wave each), all co-resident
// (no LDS, ~2 blocks/CU). Block: z = bid>>8 (layer), nt = (bid&255)>>2
// (16-col n-tile), mq = bid&3 (16-row m-tile). Each wave computes one 16x16
// C tile with full-K accumulation; 257 phases; two-level grid barrier
// (8 padded counter lines, monotone targets, master block 0 sets gen).
// ---------------------------------------------------------------------------
__global__ __launch_bounds__(64)
void rnn_mfma(const float* __restrict__ x,
              const unsigned short* __restrict__ wih0h, const unsigned short* __restrict__ wih0l,
              const unsigned short* __restrict__ whh0h, const unsigned short* __restrict__ whh0l,
              const unsigned short* __restrict__ wih1h, const unsigned short* __restrict__ wih1l,
              const unsigned short* __restrict__ whh1h, const unsigned short* __restrict__ whh1l,
              unsigned short* h1hi, unsigned short* h1lo,
              unsigned short* h2hi, unsigned short* h2lo,
              float* h2f, int* bar) {
    const int bid  = blockIdx.x;
    const int z    = bid >> 8;            // layer
    const int r    = bid & 255;
    const int nt   = r >> 2;              // 0..63
    const int mq   = r & 3;               // 0..3
    const int m0   = mq * 16;
    const int n0   = nt * 16;
    const int lane = threadIdx.x;
    const int arow = m0 + (lane & 15);    // A row (batch index)
    const int wrow = n0 + (lane & 15);    // B row (output column n)
    const int koff = (lane >> 4) * 8;     // k quad offset within chunk

    int* cnt = bar;                       // 8 lines at stride 32 ints
    int* gen = bar + 256;

    for (int p = 0; p <= T_STEPS; ++p) {
        const bool work = z ? (p >= 1) : (p < T_STEPS);
        if (work) {
            f32x4 acc = {0.f, 0.f, 0.f, 0.f};
            unsigned short *ohi, *olo;
            if (z == 0) {
                // h1' = relu(W_ih0 x_p + W_hh0 h1)
                const size_t hb = (size_t)(p & 1) * HSZ;
                seg_f32A(x + ((size_t)arow * T_STEPS + p) * DIN + koff,
                         wih0h + (size_t)wrow * DIN + koff,
                         wih0l + (size_t)wrow * DIN + koff, DIN, acc);
                seg_bf16(h1hi + hb + (size_t)arow * HID + koff,
                         h1lo + hb + (size_t)arow * HID + koff,
                         whh0h + (size_t)wrow * HID + koff,
                         whh0l + (size_t)wrow * HID + koff, HID, acc);
                const size_t ob = (size_t)((p + 1) & 1) * HSZ;
                ohi = h1hi + ob; olo = h1lo + ob;
            } else {
                // q = p-1: h2' = relu(W_ih1 h1_{q+1} + W_hh1 h2_q)
                const int q = p - 1;
                const size_t b1 = (size_t)(p & 1) * HSZ;
                const size_t b2 = (size_t)(q & 1) * HSZ;
                seg_bf16(h1hi + b1 + (size_t)arow * HID + koff,
                         h1lo + b1 + (size_t)arow * HID + koff,
                         wih1h + (size_t)wrow * HID + koff,
                         wih1l + (size_t)wrow * HID + koff, HID, acc);
                seg_bf16(h2hi + b2 + (size_t)arow * HID + koff,
                         h2lo + b2 + (size_t)arow * HID + koff,
                         whh1h + (size_t)wrow * HID + koff,
                         whh1l + (size_t)wrow * HID + koff, HID, acc);
                const size_t ob = (size_t)((q + 1) & 1) * HSZ;
                ohi = h2hi + ob; olo = h2lo + ob;
            }
            // C/D layout: col = lane&15 (n), row = (lane>>4)*4 + i (m)
#pragma unroll
            for (int i = 0; i < 4; ++i) {
                const int m = m0 + (lane >> 4) * 4 + i;
                const int n = n0 + (lane & 15);
                const float v = fmaxf(acc[i], 0.f);
                const unsigned short h = rne_bf16(v);
                ohi[(size_t)m * HID + n] = h;
                olo[(size_t)m * HID + n] = rne_bf16(v - bf16_to_f(h));
                if (z) h2f[(size_t)m * HID + n] = v;
            }
        }
        // ---- grid barrier (monotone counters, no reset race) ----
        __threadfence();
        if (lane == 0) {
            __hip_atomic_fetch_add(&cnt[(bid & 7) * 32], 1,
                                   __ATOMIC_RELEASE, __HIP_MEMORY_SCOPE_AGENT);
            if (bid == 0) {
                const int target = NBLK * (p + 1);
                for (long it = 0; it < 20000000L; ++it) {
                    int s = 0;
#pragma unroll
                    for (int i = 0; i < 8; ++i)
                        s += __hip_atomic_load(&cnt[i * 32], __ATOMIC_ACQUIRE,
                                               __HIP_MEMORY_SCOPE_AGENT);
                    if (s >= target) break;
                    __builtin_amdgcn_s_sleep(1);
                }
                __hip_atomic_store(gen, p + 1, __ATOMIC_RELEASE,
                                   __HIP_MEMORY_SCOPE_AGENT);
            } else {
                for (long it = 0; it < 20000000L; ++it) {
                    if (__hip_atomic_load(gen, __ATOMIC_ACQUIRE,
                                          __HIP_MEMORY_SCOPE_AGENT) >= p + 1)
                        break;
                    __builtin_amdgcn_s_sleep(1);
                }
            }
        }
        __syncthreads();
        __threadfence();
    }
}

// fp32 -> bf16 hi/lo splitter for weights
__global__ void split_w(const float* __restrict__ src,
                        unsigned short* __restrict__ hi,
                        unsigned short* __restrict__ lo, int n) {
    int i = blockIdx.x * 256 + threadIdx.x;
    if (i < n) {
        float v = src[i];
        unsigned short h = rne_bf16(v);
        hi[i] = h;
        lo[i] = rne_bf16(v - bf16_to_f(h));
    }
}

__global__ void zero_kernel(int* __restrict__ p, int n) {
    int i = blockIdx.x * 256 + threadIdx.x;
    if (i < n) p[i] = 0;
}

// out[b][c] = sum_k h2[b][k] * w_fc[c][k];  grid (64, 4) x 256
__global__ void fc_kernel(const float* __restrict__ h2,
                          const float* __restrict__ w_fc,
                          float* __restrict__ out) {
    __shared__ float hs[HID];
    const int b = blockIdx.x;
    for (int i = threadIdx.x; i < HID; i += 256) hs[i] = h2[(size_t)b * HID + i];
    __syncthreads();
    const int c = blockIdx.y * 256 + threadIdx.x;
    if (c < NCLS) {
        const float* w = w_fc + (size_t)c * HID;
        float s = 0.f;
        for (int k = 0; k < HID; k += 4) {
            float4 wv = *(const float4*)(w + k);
            s += wv.x * hs[k] + wv.y * hs[k + 1] + wv.z * hs[k + 2] + wv.w * hs[k + 3];
        }
        out[(size_t)b * NCLS + c] = s;
    }
}

extern "C" void kernel_launch(void* const* d_in, const int* in_sizes, int n_in,
                              void* d_out, int out_size, void* d_ws, size_t ws_size,
                              hipStream_t stream) {
    const float* x     = (const float*)d_in[0];
    const float* w_ih0 = (const float*)d_in[1];
    const float* w_hh0 = (const float*)d_in[2];
    const float* w_ih1 = (const float*)d_in[3];
    const float* w_hh1 = (const float*)d_in[4];
    const float* w_fc  = (const float*)d_in[5];
    float* out = (float*)d_out;

    char* ws = (char*)d_ws;
    const size_t MB = 1u << 20;
    unsigned short* wih0h = (unsigned short*)(ws);            // 1 MB
    unsigned short* wih0l = (unsigned short*)(ws + 1 * MB);   // 1 MB
    unsigned short* whh0h = (unsigned short*)(ws + 2 * MB);   // 2 MB
    unsigned short* whh0l = (unsigned short*)(ws + 4 * MB);
    unsigned short* wih1h = (unsigned short*)(ws + 6 * MB);
    unsigned short* wih1l = (unsigned short*)(ws + 8 * MB);
    unsigned short* whh1h = (unsigned short*)(ws + 10 * MB);
    unsigned short* whh1l = (unsigned short*)(ws + 12 * MB);
    unsigned short* h1hi  = (unsigned short*)(ws + 14 * MB);  // 2*HSZ each
    unsigned short* h1lo  = h1hi + 2 * HSZ;
    unsigned short* h2hi  = h1lo + 2 * HSZ;
    unsigned short* h2lo  = h2hi + 2 * HSZ;
    float*          h2f   = (float*)(h2lo + 2 * HSZ);         // HSZ floats
    int*            bar   = (int*)(h2f + HSZ);                // 257+ ints

    // split weights to bf16 hi/lo (every call; inputs restored each run)
    split_w<<<(DIN * HID + 255) / 256, 256, 0, stream>>>(w_ih0, wih0h, wih0l, DIN * HID);
    split_w<<<(HID * HID + 255) / 256, 256, 0, stream>>>(w_hh0, whh0h, whh0l, HID * HID);
    split_w<<<(HID * HID + 255) / 256, 256, 0, stream>>>(w_ih1, wih1h, wih1l, HID * HID);
    split_w<<<(HID * HID + 255) / 256, 256, 0, stream>>>(w_hh1, whh1h, whh1l, HID * HID);

    // zero h buffers + h2f + barrier state (ws is poisoned 0xAA each call)
    const int nzero = (8 * HSZ * 2 + HSZ * 4 + 2048) / 4;
    zero_kernel<<<(nzero + 255) / 256, 256, 0, stream>>>((int*)h1hi, nzero);

    rnn_mfma<<<NBLK, 64, 0, stream>>>(x,
                                      wih0h, wih0l, whh0h, whh0l,
                                      wih1h, wih1l, whh1h, whh1l,
                                      h1hi, h1lo, h2hi, h2lo, h2f, bar);

    fc_kernel<<<dim3(64, 4), 256, 0, stream>>>(h2f, w_fc, out);
}

// Round 4
// 14202.597 us; speedup vs baseline: 4.8108x; 2.3170x over previous
//
#include <hip/hip_runtime.h>

#define T_STEPS 256
#define BATCH   64
#define HID     1024
#define DIN     512
#define NCLS    1000
#define NBLK    128
#define HSZ     (BATCH * HID)

typedef __attribute__((ext_vector_type(8))) short  short8;  // 8 bf16
typedef __attribute__((ext_vector_type(4))) float  f32x4;   // MFMA C/D

__device__ __forceinline__ unsigned short rne_bf16(float f) {
    unsigned int u = __builtin_bit_cast(unsigned int, f);
    u += 0x7FFFu + ((u >> 16) & 1u);
    return (unsigned short)(u >> 16);
}
__device__ __forceinline__ float bf16_to_f(unsigned short h) {
    unsigned int u = ((unsigned int)h) << 16;
    return __builtin_bit_cast(float, u);
}

#define MFMA(a, b, c) __builtin_amdgcn_mfma_f32_16x16x32_bf16((a), (b), (c), 0, 0, 0)

// grid barrier: monotone counters on 8 padded lines, master = block 0.
// Pattern (agent-scope acquire/release + threadfence) validated in rounds 2-3.
__device__ __forceinline__ void grid_bar(int* cnt, int* gen, int bid, int tid, int p) {
    __threadfence();
    if (tid == 0) {
        __hip_atomic_fetch_add(&cnt[(bid & 7) * 32], 1,
                               __ATOMIC_RELEASE, __HIP_MEMORY_SCOPE_AGENT);
        if (bid == 0) {
            const int target = NBLK * (p + 1);
            for (long it = 0; it < 50000000L; ++it) {
                int s = 0;
#pragma unroll
                for (int i = 0; i < 8; ++i)
                    s += __hip_atomic_load(&cnt[i * 32], __ATOMIC_ACQUIRE,
                                           __HIP_MEMORY_SCOPE_AGENT);
                if (s >= target) break;
                __builtin_amdgcn_s_sleep(1);
            }
            __hip_atomic_store(gen, p + 1, __ATOMIC_RELEASE, __HIP_MEMORY_SCOPE_AGENT);
        } else {
            for (long it = 0; it < 50000000L; ++it) {
                if (__hip_atomic_load(gen, __ATOMIC_ACQUIRE,
                                      __HIP_MEMORY_SCOPE_AGENT) >= p + 1)
                    break;
                __builtin_amdgcn_s_sleep(1);
            }
        }
    }
    __syncthreads();
    __threadfence();
}

// reduce 8 wave-partials from LDS, relu, split to bf16 hi/lo, store.
// red layout: [wave][m:32][n:32+2pad] floats (stride 34 -> <=2-way conflicts)
__device__ __forceinline__ void reduce_store(const float* red, int tid,
                                             int mbase, int nbase,
                                             unsigned short* ohi, unsigned short* olo,
                                             float* of) {
    const int m = tid >> 4;
    const int n = (tid * 2) & 31;
    float s0 = 0.f, s1 = 0.f;
#pragma unroll
    for (int ww = 0; ww < 8; ++ww) {
        const float* rp = red + ww * 1088 + m * 34 + n;
        s0 += rp[0];
        s1 += rp[1];
    }
    const float v0 = fmaxf(s0, 0.f), v1 = fmaxf(s1, 0.f);
    const unsigned short h0 = rne_bf16(v0), h1 = rne_bf16(v1);
    const unsigned int hp = (unsigned int)h0 | ((unsigned int)h1 << 16);
    const unsigned int lp = (unsigned int)rne_bf16(v0 - bf16_to_f(h0)) |
                            ((unsigned int)rne_bf16(v1 - bf16_to_f(h1)) << 16);
    const size_t o = (size_t)(mbase + m) * HID + nbase + n;
    *(unsigned int*)(ohi + o) = hp;
    *(unsigned int*)(olo + o) = lp;
    if (of) { float2 f2; f2.x = v0; f2.y = v1; *(float2*)(of + o) = f2; }
}

// ---------------------------------------------------------------------------
// Persistent MFMA RNN, W register-resident.
// 128 blocks x 512 threads (8 waves, 1 block/CU). bid: z = bid>>6 (layer),
// r = bid&63: ngrp = r>>1 (32 cols), mgrp = r&1 (32 batch rows).
// Wave w owns a K-slice; W hi/lo fragments preloaded to VGPRs once.
// Per phase: MFMA from registers (A streamed from L2/L3), LDS partial
// reduction, relu + bf16 hi/lo split, grid barrier. 257 phases.
// ---------------------------------------------------------------------------
__global__ __launch_bounds__(512, 2)
void rnn_mfma(const unsigned short* __restrict__ xh, const unsigned short* __restrict__ xl,
              const unsigned short* __restrict__ wih0h, const unsigned short* __restrict__ wih0l,
              const unsigned short* __restrict__ whh0h, const unsigned short* __restrict__ whh0l,
              const unsigned short* __restrict__ wih1h, const unsigned short* __restrict__ wih1l,
              const unsigned short* __restrict__ whh1h, const unsigned short* __restrict__ whh1l,
              unsigned short* h1hi, unsigned short* h1lo,
              unsigned short* h2hi, unsigned short* h2lo,
              float* h2f, int* bar) {
    __shared__ float red[8 * 1088];   // 34.8 KB

    const int bid   = blockIdx.x;
    const int z     = bid >> 6;
    const int r     = bid & 63;
    const int nbase = (r >> 1) * 32;
    const int mbase = (r & 1) * 32;
    const int tid   = threadIdx.x;
    const int w     = tid >> 6;
    const int lane  = tid & 63;
    const int l15   = lane & 15;
    const int kq    = (lane >> 4) * 8;

    int* cnt = bar;
    int* gen = bar + 256;

    if (z == 0) {
        // ---- layer 1: K = 1536 (chunks 0..15 = x, 16..47 = h1). wave: 6 chunks
        short8 WH[2][6], WL[2][6];
        const int cg0 = w * 6;
#pragma unroll
        for (int c = 0; c < 6; ++c) {
            const int cg = cg0 + c;
            const unsigned short *ph, *pl;
            int rl, ko;
            if (cg < 16) { ph = wih0h; pl = wih0l; rl = DIN; ko = cg * 32; }
            else         { ph = whh0h; pl = whh0l; rl = HID; ko = (cg - 16) * 32; }
#pragma unroll
            for (int nt = 0; nt < 2; ++nt) {
                const size_t o = (size_t)(nbase + nt * 16 + l15) * rl + ko + kq;
                WH[nt][c] = *(const short8*)(ph + o);
                WL[nt][c] = *(const short8*)(pl + o);
            }
        }
        for (int p = 0; p <= T_STEPS; ++p) {
            if (p < T_STEPS) {
                f32x4 acc[2][2] = {};
                const unsigned short* h1ch = h1hi + (size_t)(p & 1) * HSZ;
                const unsigned short* h1cl = h1lo + (size_t)(p & 1) * HSZ;
#pragma unroll
                for (int c = 0; c < 6; ++c) {
                    const int cg = cg0 + c;
                    short8 ah[2], al[2];
                    if (cg < 16) {
                        const size_t b0 = (size_t)p * DIN + cg * 32 + kq;
#pragma unroll
                        for (int mt = 0; mt < 2; ++mt) {
                            const size_t o = (size_t)(mbase + mt * 16 + l15) * (T_STEPS * DIN) + b0;
                            ah[mt] = *(const short8*)(xh + o);
                            al[mt] = *(const short8*)(xl + o);
                        }
                    } else {
                        const int ko = (cg - 16) * 32 + kq;
#pragma unroll
                        for (int mt = 0; mt < 2; ++mt) {
                            const size_t o = (size_t)(mbase + mt * 16 + l15) * HID + ko;
                            ah[mt] = *(const short8*)(h1ch + o);
                            al[mt] = *(const short8*)(h1cl + o);
                        }
                    }
#pragma unroll
                    for (int mt = 0; mt < 2; ++mt)
#pragma unroll
                        for (int nt = 0; nt < 2; ++nt) {
                            acc[mt][nt] = MFMA(ah[mt], WH[nt][c], acc[mt][nt]);
                            acc[mt][nt] = MFMA(al[mt], WH[nt][c], acc[mt][nt]);
                            acc[mt][nt] = MFMA(ah[mt], WL[nt][c], acc[mt][nt]);
                        }
                }
#pragma unroll
                for (int mt = 0; mt < 2; ++mt)
#pragma unroll
                    for (int nt = 0; nt < 2; ++nt)
#pragma unroll
                        for (int i = 0; i < 4; ++i)
                            red[w * 1088 + (mt * 16 + (lane >> 4) * 4 + i) * 34 +
                                nt * 16 + l15] = acc[mt][nt][i];
                __syncthreads();
                const size_t ob = (size_t)((p + 1) & 1) * HSZ;
                reduce_store(red, tid, mbase, nbase, h1hi + ob, h1lo + ob, nullptr);
                __syncthreads();
            }
            grid_bar(cnt, gen, bid, tid, p);
        }
    } else {
        // ---- layer 2: K = 2048 (waves 0..3 = h1-next, 4..7 = h2-cur). 8 chunks
        short8 WH[2][8], WL[2][8];
        const unsigned short* ph = (w < 4) ? wih1h : whh1h;
        const unsigned short* pl = (w < 4) ? wih1l : whh1l;
        const int kb = (w & 3) * 256;
#pragma unroll
        for (int c = 0; c < 8; ++c)
#pragma unroll
            for (int nt = 0; nt < 2; ++nt) {
                const size_t o = (size_t)(nbase + nt * 16 + l15) * HID + kb + c * 32 + kq;
                WH[nt][c] = *(const short8*)(ph + o);
                WL[nt][c] = *(const short8*)(pl + o);
            }
        for (int p = 0; p <= T_STEPS; ++p) {
            if (p >= 1) {
                f32x4 acc[2][2] = {};
                const unsigned short* ash = (w < 4) ? h1hi + (size_t)(p & 1) * HSZ
                                                    : h2hi + (size_t)((p - 1) & 1) * HSZ;
                const unsigned short* asl = (w < 4) ? h1lo + (size_t)(p & 1) * HSZ
                                                    : h2lo + (size_t)((p - 1) & 1) * HSZ;
#pragma unroll
                for (int c = 0; c < 8; ++c) {
                    short8 ah[2], al[2];
#pragma unroll
                    for (int mt = 0; mt < 2; ++mt) {
                        const size_t o = (size_t)(mbase + mt * 16 + l15) * HID + kb + c * 32 + kq;
                        ah[mt] = *(const short8*)(ash + o);
                        al[mt] = *(const short8*)(asl + o);
                    }
#pragma unroll
                    for (int mt = 0; mt < 2; ++mt)
#pragma unroll
                        for (int nt = 0; nt < 2; ++nt) {
                            acc[mt][nt] = MFMA(ah[mt], WH[nt][c], acc[mt][nt]);
                            acc[mt][nt] = MFMA(al[mt], WH[nt][c], acc[mt][nt]);
                            acc[mt][nt] = MFMA(ah[mt], WL[nt][c], acc[mt][nt]);
                        }
                }
#pragma unroll
                for (int mt = 0; mt < 2; ++mt)
#pragma unroll
                    for (int nt = 0; nt < 2; ++nt)
#pragma unroll
                        for (int i = 0; i < 4; ++i)
                            red[w * 1088 + (mt * 16 + (lane >> 4) * 4 + i) * 34 +
                                nt * 16 + l15] = acc[mt][nt][i];
                __syncthreads();
                const size_t ob = (size_t)(p & 1) * HSZ;
                reduce_store(red, tid, mbase, nbase, h2hi + ob, h2lo + ob,
                             (p == T_STEPS) ? h2f : nullptr);
                __syncthreads();
            }
            grid_bar(cnt, gen, bid, tid, p);
        }
    }
}

// fp32 -> bf16 hi/lo splitter
__global__ void split_w(const float* __restrict__ src,
                        unsigned short* __restrict__ hi,
                        unsigned short* __restrict__ lo, int n) {
    int i = blockIdx.x * 256 + threadIdx.x;
    if (i < n) {
        float v = src[i];
        unsigned short h = rne_bf16(v);
        hi[i] = h;
        lo[i] = rne_bf16(v - bf16_to_f(h));
    }
}

__global__ void zero_kernel(int* __restrict__ p, int n) {
    int i = blockIdx.x * 256 + threadIdx.x;
    if (i < n) p[i] = 0;
}

__global__ void fc_kernel(const float* __restrict__ h2,
                          const float* __restrict__ w_fc,
                          float* __restrict__ out) {
    __shared__ float hs[HID];
    const int b = blockIdx.x;
    for (int i = threadIdx.x; i < HID; i += 256) hs[i] = h2[(size_t)b * HID + i];
    __syncthreads();
    const int c = blockIdx.y * 256 + threadIdx.x;
    if (c < NCLS) {
        const float* w = w_fc + (size_t)c * HID;
        float s = 0.f;
        for (int k = 0; k < HID; k += 4) {
            float4 wv = *(const float4*)(w + k);
            s += wv.x * hs[k] + wv.y * hs[k + 1] + wv.z * hs[k + 2] + wv.w * hs[k + 3];
        }
        out[(size_t)b * NCLS + c] = s;
    }
}

extern "C" void kernel_launch(void* const* d_in, const int* in_sizes, int n_in,
                              void* d_out, int out_size, void* d_ws, size_t ws_size,
                              hipStream_t stream) {
    const float* x     = (const float*)d_in[0];
    const float* w_ih0 = (const float*)d_in[1];
    const float* w_hh0 = (const float*)d_in[2];
    const float* w_ih1 = (const float*)d_in[3];
    const float* w_hh1 = (const float*)d_in[4];
    const float* w_fc  = (const float*)d_in[5];
    float* out = (float*)d_out;

    char* ws = (char*)d_ws;
    size_t off = 0;
    auto alloc = [&](size_t bytes) { char* p = ws + off; off += bytes; return p; };
    const size_t XEL = (size_t)BATCH * T_STEPS * DIN;   // 8.4M
    unsigned short* xh    = (unsigned short*)alloc(XEL * 2);
    unsigned short* xl    = (unsigned short*)alloc(XEL * 2);
    unsigned short* wih0h = (unsigned short*)alloc((size_t)DIN * HID * 2);
    unsigned short* wih0l = (unsigned short*)alloc((size_t)DIN * HID * 2);
    unsigned short* whh0h = (unsigned short*)alloc((size_t)HID * HID * 2);
    unsigned short* whh0l = (unsigned short*)alloc((size_t)HID * HID * 2);
    unsigned short* wih1h = (unsigned short*)alloc((size_t)HID * HID * 2);
    unsigned short* wih1l = (unsigned short*)alloc((size_t)HID * HID * 2);
    unsigned short* whh1h = (unsigned short*)alloc((size_t)HID * HID * 2);
    unsigned short* whh1l = (unsigned short*)alloc((size_t)HID * HID * 2);
    unsigned short* h1hi  = (unsigned short*)alloc(2 * HSZ * 2);
    unsigned short* h1lo  = (unsigned short*)alloc(2 * HSZ * 2);
    unsigned short* h2hi  = (unsigned short*)alloc(2 * HSZ * 2);
    unsigned short* h2lo  = (unsigned short*)alloc(2 * HSZ * 2);
    float*          h2f   = (float*)alloc(HSZ * 4);
    int*            bar   = (int*)alloc(4096);

    // split inputs to bf16 hi/lo (numerics identical to round-3 on-the-fly)
    split_w<<<((int)XEL + 255) / 256, 256, 0, stream>>>(x, xh, xl, (int)XEL);
    split_w<<<(DIN * HID + 255) / 256, 256, 0, stream>>>(w_ih0, wih0h, wih0l, DIN * HID);
    split_w<<<(HID * HID + 255) / 256, 256, 0, stream>>>(w_hh0, whh0h, whh0l, HID * HID);
    split_w<<<(HID * HID + 255) / 256, 256, 0, stream>>>(w_ih1, wih1h, wih1l, HID * HID);
    split_w<<<(HID * HID + 255) / 256, 256, 0, stream>>>(w_hh1, whh1h, whh1l, HID * HID);

    // zero h states + h2f + barrier (contiguous tail region)
    const int nzero = (4 * (2 * HSZ * 2) + HSZ * 4 + 4096) / 4;
    zero_kernel<<<(nzero + 255) / 256, 256, 0, stream>>>((int*)h1hi, nzero);

    rnn_mfma<<<NBLK, 512, 0, stream>>>(xh, xl,
                                       wih0h, wih0l, whh0h, whh0l,
                                       wih1h, wih1l, whh1h, whh1l,
                                       h1hi, h1lo, h2hi, h2lo, h2f, bar);

    fc_kernel<<<dim3(64, 4), 256, 0, stream>>>(h2f, w_fc, out);
}

// Round 5
// 3980.528 us; speedup vs baseline: 17.1651x; 3.5680x over previous
//
#include <hip/hip_runtime.h>

#define T_STEPS 256
#define BATCH   64
#define HID     1024
#define DIN     512
#define NCLS    1000
#define NBLK    128
#define HSZ     (BATCH * HID)

typedef __attribute__((ext_vector_type(8))) short  short8;  // 8 bf16
typedef __attribute__((ext_vector_type(4))) float  f32x4;   // MFMA C/D

__device__ __forceinline__ unsigned short rne_bf16(float f) {
    unsigned int u = __builtin_bit_cast(unsigned int, f);
    u += 0x7FFFu + ((u >> 16) & 1u);
    return (unsigned short)(u >> 16);
}
__device__ __forceinline__ float bf16_to_f(unsigned short h) {
    unsigned int u = ((unsigned int)h) << 16;
    return __builtin_bit_cast(float, u);
}

#define MFMA(a, b, c) __builtin_amdgcn_mfma_f32_16x16x32_bf16((a), (b), (c), 0, 0, 0)

// ---------------------------------------------------------------------------
// Grid barrier, fence-hygienic version. __syncthreads() drains all waves'
// vmcnt (stores reach L2) before s_barrier; then exactly ONE release fence
// (L2 writeback) and ONE acquire fence (L1/L2 invalidate) per block per
// phase, executed by tid 0 only. Polling uses RELAXED agent atomics, which
// read the coherence point without per-iteration cache invalidation.
// Round-4's per-thread fences caused ~2048 L2 wb/inv per block-phase.
// ---------------------------------------------------------------------------
__device__ __forceinline__ void grid_bar(int* cnt, int* gen, int bid, int tid, int p) {
    __syncthreads();
    if (tid == 0) {
        __threadfence();   // release: push this block's stores to coherence point
        __hip_atomic_fetch_add(&cnt[(bid & 7) * 32], 1,
                               __ATOMIC_RELAXED, __HIP_MEMORY_SCOPE_AGENT);
        if (bid == 0) {
            const int target = NBLK * (p + 1);
            for (long it = 0; it < 1000000L; ++it) {
                int s = 0;
#pragma unroll
                for (int i = 0; i < 8; ++i)
                    s += __hip_atomic_load(&cnt[i * 32], __ATOMIC_RELAXED,
                                           __HIP_MEMORY_SCOPE_AGENT);
                if (s >= target) break;
                __builtin_amdgcn_s_sleep(1);
            }
            __threadfence();
            __hip_atomic_store(gen, p + 1, __ATOMIC_RELAXED, __HIP_MEMORY_SCOPE_AGENT);
        } else {
            for (long it = 0; it < 1000000L; ++it) {
                if (__hip_atomic_load(gen, __ATOMIC_RELAXED,
                                      __HIP_MEMORY_SCOPE_AGENT) >= p + 1)
                    break;
                __builtin_amdgcn_s_sleep(1);
            }
            __threadfence();   // acquire: invalidate stale L1/L2 before reads
        }
    }
    __syncthreads();
}

// reduce 8 wave-partials from LDS (+ optional fp32 xproj tile), relu,
// split to bf16 hi/lo, store. red: [wave][m:32][n:34] floats.
__device__ __forceinline__ void reduce_store(const float* red, int tid,
                                             int mbase, int nbase,
                                             unsigned short* ohi, unsigned short* olo,
                                             float* of, const float* xp) {
    const int m = tid >> 4;
    const int n = (tid * 2) & 31;
    float s0, s1;
    if (xp) {
        float2 xi = *(const float2*)(xp + (size_t)(mbase + m) * HID + nbase + n);
        s0 = xi.x; s1 = xi.y;
    } else { s0 = 0.f; s1 = 0.f; }
#pragma unroll
    for (int ww = 0; ww < 8; ++ww) {
        const float* rp = red + ww * 1088 + m * 34 + n;
        s0 += rp[0];
        s1 += rp[1];
    }
    const float v0 = fmaxf(s0, 0.f), v1 = fmaxf(s1, 0.f);
    const unsigned short h0 = rne_bf16(v0), h1 = rne_bf16(v1);
    const unsigned int hp = (unsigned int)h0 | ((unsigned int)h1 << 16);
    const unsigned int lp = (unsigned int)rne_bf16(v0 - bf16_to_f(h0)) |
                            ((unsigned int)rne_bf16(v1 - bf16_to_f(h1)) << 16);
    const size_t o = (size_t)(mbase + m) * HID + nbase + n;
    *(unsigned int*)(ohi + o) = hp;
    *(unsigned int*)(olo + o) = lp;
    if (of) { float2 f2; f2.x = v0; f2.y = v1; *(float2*)(of + o) = f2; }
}

// ---------------------------------------------------------------------------
// Persistent MFMA RNN. 128 blocks x 512 threads (8 waves). bid: z = bid>>6,
// r = bid&63: nbase = (r>>1)*32, mbase = (r&1)*32.
// Layer 1: K = 1024 (h1 only; x-projection precomputed into xproj and added
// in reduce_store). Layer 2: K = 2048 (waves 0..3 h1-next, 4..7 h2-cur).
// ---------------------------------------------------------------------------
__global__ __launch_bounds__(512, 2)
void rnn_mfma(const float* __restrict__ xproj,
              const unsigned short* __restrict__ whh0h, const unsigned short* __restrict__ whh0l,
              const unsigned short* __restrict__ wih1h, const unsigned short* __restrict__ wih1l,
              const unsigned short* __restrict__ whh1h, const unsigned short* __restrict__ whh1l,
              unsigned short* h1hi, unsigned short* h1lo,
              unsigned short* h2hi, unsigned short* h2lo,
              float* h2f, int* bar) {
    __shared__ float red[8 * 1088];   // 34.8 KB

    const int bid   = blockIdx.x;
    const int z     = bid >> 6;
    const int r     = bid & 63;
    const int nbase = (r >> 1) * 32;
    const int mbase = (r & 1) * 32;
    const int tid   = threadIdx.x;
    const int w     = tid >> 6;
    const int lane  = tid & 63;
    const int l15   = lane & 15;
    const int kq    = (lane >> 4) * 8;

    int* cnt = bar;
    int* gen = bar + 256;

    if (z == 0) {
        // ---- layer 1: K = 1024, wave w owns k in [w*128, w*128+128)
        short8 WH[2][4], WL[2][4];
        const int kb = w * 128;
#pragma unroll
        for (int c = 0; c < 4; ++c)
#pragma unroll
            for (int nt = 0; nt < 2; ++nt) {
                const size_t o = (size_t)(nbase + nt * 16 + l15) * HID + kb + c * 32 + kq;
                WH[nt][c] = *(const short8*)(whh0h + o);
                WL[nt][c] = *(const short8*)(whh0l + o);
            }
        for (int p = 0; p <= T_STEPS; ++p) {
            if (p < T_STEPS) {
                f32x4 acc[2][2] = {};
                const unsigned short* hch = h1hi + (size_t)(p & 1) * HSZ;
                const unsigned short* hcl = h1lo + (size_t)(p & 1) * HSZ;
#pragma unroll
                for (int c = 0; c < 4; ++c) {
                    short8 ah[2], al[2];
#pragma unroll
                    for (int mt = 0; mt < 2; ++mt) {
                        const size_t o = (size_t)(mbase + mt * 16 + l15) * HID + kb + c * 32 + kq;
                        ah[mt] = *(const short8*)(hch + o);
                        al[mt] = *(const short8*)(hcl + o);
                    }
#pragma unroll
                    for (int mt = 0; mt < 2; ++mt)
#pragma unroll
                        for (int nt = 0; nt < 2; ++nt) {
                            acc[mt][nt] = MFMA(ah[mt], WH[nt][c], acc[mt][nt]);
                            acc[mt][nt] = MFMA(al[mt], WH[nt][c], acc[mt][nt]);
                            acc[mt][nt] = MFMA(ah[mt], WL[nt][c], acc[mt][nt]);
                        }
                }
#pragma unroll
                for (int mt = 0; mt < 2; ++mt)
#pragma unroll
                    for (int nt = 0; nt < 2; ++nt)
#pragma unroll
                        for (int i = 0; i < 4; ++i)
                            red[w * 1088 + (mt * 16 + (lane >> 4) * 4 + i) * 34 +
                                nt * 16 + l15] = acc[mt][nt][i];
                __syncthreads();
                const size_t ob = (size_t)((p + 1) & 1) * HSZ;
                reduce_store(red, tid, mbase, nbase, h1hi + ob, h1lo + ob, nullptr,
                             xproj + (size_t)p * BATCH * HID);
            }
            grid_bar(cnt, gen, bid, tid, p);
        }
    } else {
        // ---- layer 2: K = 2048 (waves 0..3 = h1-next, 4..7 = h2-cur)
        short8 WH[2][8], WL[2][8];
        const unsigned short* ph = (w < 4) ? wih1h : whh1h;
        const unsigned short* pl = (w < 4) ? wih1l : whh1l;
        const int kb = (w & 3) * 256;
#pragma unroll
        for (int c = 0; c < 8; ++c)
#pragma unroll
            for (int nt = 0; nt < 2; ++nt) {
                const size_t o = (size_t)(nbase + nt * 16 + l15) * HID + kb + c * 32 + kq;
                WH[nt][c] = *(const short8*)(ph + o);
                WL[nt][c] = *(const short8*)(pl + o);
            }
        for (int p = 0; p <= T_STEPS; ++p) {
            if (p >= 1) {
                f32x4 acc[2][2] = {};
                const unsigned short* ash = (w < 4) ? h1hi + (size_t)(p & 1) * HSZ
                                                    : h2hi + (size_t)((p - 1) & 1) * HSZ;
                const unsigned short* asl = (w < 4) ? h1lo + (size_t)(p & 1) * HSZ
                                                    : h2lo + (size_t)((p - 1) & 1) * HSZ;
#pragma unroll
                for (int c = 0; c < 8; ++c) {
                    short8 ah[2], al[2];
#pragma unroll
                    for (int mt = 0; mt < 2; ++mt) {
                        const size_t o = (size_t)(mbase + mt * 16 + l15) * HID + kb + c * 32 + kq;
                        ah[mt] = *(const short8*)(ash + o);
                        al[mt] = *(const short8*)(asl + o);
                    }
#pragma unroll
                    for (int mt = 0; mt < 2; ++mt)
#pragma unroll
                        for (int nt = 0; nt < 2; ++nt) {
                            acc[mt][nt] = MFMA(ah[mt], WH[nt][c], acc[mt][nt]);
                            acc[mt][nt] = MFMA(al[mt], WH[nt][c], acc[mt][nt]);
                            acc[mt][nt] = MFMA(ah[mt], WL[nt][c], acc[mt][nt]);
                        }
                }
#pragma unroll
                for (int mt = 0; mt < 2; ++mt)
#pragma unroll
                    for (int nt = 0; nt < 2; ++nt)
#pragma unroll
                        for (int i = 0; i < 4; ++i)
                            red[w * 1088 + (mt * 16 + (lane >> 4) * 4 + i) * 34 +
                                nt * 16 + l15] = acc[mt][nt][i];
                __syncthreads();
                const size_t ob = (size_t)(p & 1) * HSZ;
                reduce_store(red, tid, mbase, nbase, h2hi + ob, h2lo + ob,
                             (p == T_STEPS) ? h2f : nullptr, nullptr);
            }
            grid_bar(cnt, gen, bid, tid, p);
        }
    }
}

// ---------------------------------------------------------------------------
// Bulk x-projection: xproj[t][b][n] = sum_k x[b][t][k] * w_ih0[n][k],
// 3-pass Markidis with on-the-fly fp32->bf16 hi/lo split of x.
// grid (T, 4 n-quarters) x 512; wave w -> 32 cols, all 64 batch rows.
// ---------------------------------------------------------------------------
__global__ __launch_bounds__(512)
void xproj_gemm(const float* __restrict__ x,
                const unsigned short* __restrict__ wh,
                const unsigned short* __restrict__ wl,
                float* __restrict__ xproj) {
    const int t    = blockIdx.x;
    const int nq   = blockIdx.y;
    const int w    = threadIdx.x >> 6;
    const int lane = threadIdx.x & 63;
    const int l15  = lane & 15;
    const int kq   = (lane >> 4) * 8;
    const int n0   = nq * 256 + w * 32;

    f32x4 acc[4][2] = {};
    for (int c = 0; c < 16; ++c) {
        const int k = c * 32 + kq;
        short8 wfh[2], wfl[2];
#pragma unroll
        for (int nt = 0; nt < 2; ++nt) {
            const size_t o = (size_t)(n0 + nt * 16 + l15) * DIN + k;
            wfh[nt] = *(const short8*)(wh + o);
            wfl[nt] = *(const short8*)(wl + o);
        }
#pragma unroll
        for (int mt = 0; mt < 4; ++mt) {
            const float* xr = x + ((size_t)(mt * 16 + l15) * T_STEPS + t) * DIN + k;
            float4 a0 = *(const float4*)xr;
            float4 a1 = *(const float4*)(xr + 4);
            float f[8] = {a0.x, a0.y, a0.z, a0.w, a1.x, a1.y, a1.z, a1.w};
            short8 ah, al;
#pragma unroll
            for (int i = 0; i < 8; ++i) {
                unsigned short h = rne_bf16(f[i]);
                ah[i] = (short)h;
                al[i] = (short)rne_bf16(f[i] - bf16_to_f(h));
            }
#pragma unroll
            for (int nt = 0; nt < 2; ++nt) {
                acc[mt][nt] = MFMA(ah, wfh[nt], acc[mt][nt]);
                acc[mt][nt] = MFMA(al, wfh[nt], acc[mt][nt]);
                acc[mt][nt] = MFMA(ah, wfl[nt], acc[mt][nt]);
            }
        }
    }
    float* op = xproj + (size_t)t * BATCH * HID;
#pragma unroll
    for (int mt = 0; mt < 4; ++mt)
#pragma unroll
        for (int nt = 0; nt < 2; ++nt)
#pragma unroll
            for (int i = 0; i < 4; ++i) {
                const int m = mt * 16 + (lane >> 4) * 4 + i;
                const int n = n0 + nt * 16 + l15;
                op[(size_t)m * HID + n] = acc[mt][nt][i];
            }
}

__global__ void split_w(const float* __restrict__ src,
                        unsigned short* __restrict__ hi,
                        unsigned short* __restrict__ lo, int n) {
    int i = blockIdx.x * 256 + threadIdx.x;
    if (i < n) {
        float v = src[i];
        unsigned short h = rne_bf16(v);
        hi[i] = h;
        lo[i] = rne_bf16(v - bf16_to_f(h));
    }
}

__global__ void zero_kernel(int* __restrict__ p, int n) {
    int i = blockIdx.x * 256 + threadIdx.x;
    if (i < n) p[i] = 0;
}

__global__ void fc_kernel(const float* __restrict__ h2,
                          const float* __restrict__ w_fc,
                          float* __restrict__ out) {
    __shared__ float hs[HID];
    const int b = blockIdx.x;
    for (int i = threadIdx.x; i < HID; i += 256) hs[i] = h2[(size_t)b * HID + i];
    __syncthreads();
    const int c = blockIdx.y * 256 + threadIdx.x;
    if (c < NCLS) {
        const float* w = w_fc + (size_t)c * HID;
        float s = 0.f;
        for (int k = 0; k < HID; k += 4) {
            float4 wv = *(const float4*)(w + k);
            s += wv.x * hs[k] + wv.y * hs[k + 1] + wv.z * hs[k + 2] + wv.w * hs[k + 3];
        }
        out[(size_t)b * NCLS + c] = s;
    }
}

extern "C" void kernel_launch(void* const* d_in, const int* in_sizes, int n_in,
                              void* d_out, int out_size, void* d_ws, size_t ws_size,
                              hipStream_t stream) {
    const float* x     = (const float*)d_in[0];
    const float* w_ih0 = (const float*)d_in[1];
    const float* w_hh0 = (const float*)d_in[2];
    const float* w_ih1 = (const float*)d_in[3];
    const float* w_hh1 = (const float*)d_in[4];
    const float* w_fc  = (const float*)d_in[5];
    float* out = (float*)d_out;

    char* ws = (char*)d_ws;
    size_t off = 0;
    auto alloc = [&](size_t bytes) { char* p = ws + off; off += bytes; return p; };
    float*          xproj = (float*)alloc((size_t)T_STEPS * BATCH * HID * 4);  // 64 MB
    unsigned short* wih0h = (unsigned short*)alloc((size_t)DIN * HID * 2);
    unsigned short* wih0l = (unsigned short*)alloc((size_t)DIN * HID * 2);
    unsigned short* whh0h = (unsigned short*)alloc((size_t)HID * HID * 2);
    unsigned short* whh0l = (unsigned short*)alloc((size_t)HID * HID * 2);
    unsigned short* wih1h = (unsigned short*)alloc((size_t)HID * HID * 2);
    unsigned short* wih1l = (unsigned short*)alloc((size_t)HID * HID * 2);
    unsigned short* whh1h = (unsigned short*)alloc((size_t)HID * HID * 2);
    unsigned short* whh1l = (unsigned short*)alloc((size_t)HID * HID * 2);
    unsigned short* h1hi  = (unsigned short*)alloc(2 * HSZ * 2);
    unsigned short* h1lo  = (unsigned short*)alloc(2 * HSZ * 2);
    unsigned short* h2hi  = (unsigned short*)alloc(2 * HSZ * 2);
    unsigned short* h2lo  = (unsigned short*)alloc(2 * HSZ * 2);
    float*          h2f   = (float*)alloc(HSZ * 4);
    int*            bar   = (int*)alloc(4096);

    // split weights to bf16 hi/lo
    split_w<<<(DIN * HID + 255) / 256, 256, 0, stream>>>(w_ih0, wih0h, wih0l, DIN * HID);
    split_w<<<(HID * HID + 255) / 256, 256, 0, stream>>>(w_hh0, whh0h, whh0l, HID * HID);
    split_w<<<(HID * HID + 255) / 256, 256, 0, stream>>>(w_ih1, wih1h, wih1l, HID * HID);
    split_w<<<(HID * HID + 255) / 256, 256, 0, stream>>>(w_hh1, whh1h, whh1l, HID * HID);

    // bulk x-projection (removes x from the recurrence critical path)
    xproj_gemm<<<dim3(T_STEPS, 4), 512, 0, stream>>>(x, wih0h, wih0l, xproj);

    // zero h states + h2f + barrier (contiguous tail region)
    const int nzero = (4 * (2 * HSZ * 2) + HSZ * 4 + 4096) / 4;
    zero_kernel<<<(nzero + 255) / 256, 256, 0, stream>>>((int*)h1hi, nzero);

    rnn_mfma<<<NBLK, 512, 0, stream>>>(xproj,
                                       whh0h, whh0l,
                                       wih1h, wih1l, whh1h, whh1l,
                                       h1hi, h1lo, h2hi, h2lo, h2f, bar);

    fc_kernel<<<dim3(64, 4), 256, 0, stream>>>(h2f, w_fc, out);
}